// Round 1
// baseline (202.686 us; speedup 1.0000x reference)
//
#include <hip/hip_runtime.h>
#include <hip/hip_bf16.h>
#include <math.h>

#define DIM   256
#define NHEAD 8
#define HD    32
#define NTOK  4096
#define GRD   64
#define BATCH 2

// ---------------- GEMM: C[M,N] = A[M,K] @ B[N,K]^T (+bias) ----------------
// A row-major [M,K], Bw row-major [N,K] (so both have K contiguous: "NT").
__global__ __launch_bounds__(256) void gemm_nt(const float* __restrict__ A,
                                               const float* __restrict__ Bw,
                                               const float* __restrict__ bias,
                                               float* __restrict__ C,
                                               int M, int N, int K) {
  const int BM = 64, BN = 64, BK = 32;
  __shared__ float As[32][65];
  __shared__ float Bs[32][65];
  const int tid = threadIdx.x;
  const int bm = blockIdx.y * BM;
  const int bn = blockIdx.x * BN;
  const int tr = tid >> 4;   // 0..15
  const int tc = tid & 15;   // 0..15
  float acc[4][4] = {{0.f}};

  for (int k0 = 0; k0 < K; k0 += BK) {
    // Load A tile: BM x BK floats (row-major, k contiguous), store transposed.
    for (int i = tid; i < BM * BK / 4; i += 256) {
      int r  = i >> 3;          // BK/4 = 8 float4 per row
      int kc = (i & 7) << 2;
      float4 v = *(const float4*)&A[(size_t)(bm + r) * K + k0 + kc];
      As[kc + 0][r] = v.x; As[kc + 1][r] = v.y;
      As[kc + 2][r] = v.z; As[kc + 3][r] = v.w;
    }
    // Load B tile: BN x BK floats.
    for (int i = tid; i < BN * BK / 4; i += 256) {
      int r  = i >> 3;
      int kc = (i & 7) << 2;
      float4 v = *(const float4*)&Bw[(size_t)(bn + r) * K + k0 + kc];
      Bs[kc + 0][r] = v.x; Bs[kc + 1][r] = v.y;
      Bs[kc + 2][r] = v.z; Bs[kc + 3][r] = v.w;
    }
    __syncthreads();
    #pragma unroll
    for (int kk = 0; kk < BK; ++kk) {
      float a[4], b[4];
      #pragma unroll
      for (int i = 0; i < 4; ++i) a[i] = As[kk][tr * 4 + i];
      #pragma unroll
      for (int j = 0; j < 4; ++j) b[j] = Bs[kk][tc * 4 + j];
      #pragma unroll
      for (int i = 0; i < 4; ++i)
        #pragma unroll
        for (int j = 0; j < 4; ++j)
          acc[i][j] = fmaf(a[i], b[j], acc[i][j]);
    }
    __syncthreads();
  }

  #pragma unroll
  for (int i = 0; i < 4; ++i) {
    int row = bm + tr * 4 + i;
    #pragma unroll
    for (int j = 0; j < 4; ++j) {
      int col = bn + tc * 4 + j;
      float v = acc[i][j];
      if (bias) v += bias[col];
      C[(size_t)row * N + col] = v;
    }
  }
}

// ---------------- Local attention ----------------
// qkv layout: [B][N][768] where per token: q = [h*32 .. h*32+32), k = 256+...,
// v = 512+... . One block (64 threads = 1 wave) handles one (b, h, grid_row).
// Thread = one query (grid column c). Each query attends to keys with
// |dr|<=3, |dc|<=3 on the 64x64 grid (<=49 keys).
__global__ __launch_bounds__(64) void local_attn(const float* __restrict__ qkv,
                                                 const float* __restrict__ temp,
                                                 float* __restrict__ attn_out) {
  const int blk = blockIdx.x;
  const int r = blk & 63;
  const int h = (blk >> 6) & 7;
  const int b = blk >> 9;
  const int c = threadIdx.x;
  const int n = r * GRD + c;

  const float scale = 0.17677669529663687f * temp[0];  // 32^-0.5 * temperature

  const float* qrow = qkv + (size_t)(b * NTOK + n) * 768 + h * HD;
  float q[HD];
  #pragma unroll
  for (int i = 0; i < HD / 4; ++i) {
    float4 v = *(const float4*)&qrow[i * 4];
    q[4*i+0] = v.x; q[4*i+1] = v.y; q[4*i+2] = v.z; q[4*i+3] = v.w;
  }

  float s[49];
  float mx = -INFINITY;
  int idx = 0;
  #pragma unroll
  for (int dr = -3; dr <= 3; ++dr) {
    int rr = r + dr;
    bool vr = (rr >= 0) && (rr < GRD);
    #pragma unroll
    for (int dc = -3; dc <= 3; ++dc, ++idx) {
      int cc = c + dc;
      bool ok = vr && (cc >= 0) && (cc < GRD);
      float dot = 0.f;
      if (ok) {
        const float* krow = qkv + (size_t)(b * NTOK + rr * GRD + cc) * 768 + DIM + h * HD;
        #pragma unroll
        for (int i = 0; i < HD / 4; ++i) {
          float4 kv = *(const float4*)&krow[i * 4];
          dot = fmaf(kv.x, q[4*i+0], dot);
          dot = fmaf(kv.y, q[4*i+1], dot);
          dot = fmaf(kv.z, q[4*i+2], dot);
          dot = fmaf(kv.w, q[4*i+3], dot);
        }
        dot *= scale;
      } else {
        dot = -INFINITY;
      }
      s[idx] = dot;
      mx = fmaxf(mx, dot);
    }
  }

  float sum = 0.f;
  #pragma unroll
  for (int i = 0; i < 49; ++i) {
    float e = expf(s[i] - mx);   // exp(-inf) = 0 for masked entries
    s[i] = e;
    sum += e;
  }
  const float inv = 1.0f / sum;

  float acc[HD] = {0.f};
  idx = 0;
  #pragma unroll
  for (int dr = -3; dr <= 3; ++dr) {
    int rr = r + dr;
    bool vr = (rr >= 0) && (rr < GRD);
    #pragma unroll
    for (int dc = -3; dc <= 3; ++dc, ++idx) {
      int cc = c + dc;
      bool ok = vr && (cc >= 0) && (cc < GRD);
      if (ok) {
        float p = s[idx] * inv;
        const float* vrow = qkv + (size_t)(b * NTOK + rr * GRD + cc) * 768 + 2 * DIM + h * HD;
        #pragma unroll
        for (int i = 0; i < HD / 4; ++i) {
          float4 vv = *(const float4*)&vrow[i * 4];
          acc[4*i+0] = fmaf(p, vv.x, acc[4*i+0]);
          acc[4*i+1] = fmaf(p, vv.y, acc[4*i+1]);
          acc[4*i+2] = fmaf(p, vv.z, acc[4*i+2]);
          acc[4*i+3] = fmaf(p, vv.w, acc[4*i+3]);
        }
      }
    }
  }

  float* orow = attn_out + (size_t)(b * NTOK + n) * DIM + h * HD;
  #pragma unroll
  for (int i = 0; i < HD / 4; ++i) {
    float4 v;
    v.x = acc[4*i+0]; v.y = acc[4*i+1]; v.z = acc[4*i+2]; v.w = acc[4*i+3];
    *(float4*)&orow[i * 4] = v;
  }
}

extern "C" void kernel_launch(void* const* d_in, const int* in_sizes, int n_in,
                              void* d_out, int out_size, void* d_ws, size_t ws_size,
                              hipStream_t stream) {
  const float* x     = (const float*)d_in[0];  // [2,4096,256]
  const float* Wqkv  = (const float*)d_in[1];  // [768,256]
  const float* Wproj = (const float*)d_in[2];  // [256,256]
  const float* bproj = (const float*)d_in[3];  // [256]
  const float* temp  = (const float*)d_in[4];  // [1]
  float* out = (float*)d_out;                  // [2,4096,256]

  float* qkv  = (float*)d_ws;                          // 2*4096*768 floats
  float* attn = qkv + (size_t)BATCH * NTOK * 3 * DIM;  // 2*4096*256 floats

  const int M = BATCH * NTOK;  // 8192

  // 1) qkv = x @ Wqkv^T   -> [M, 768]
  {
    dim3 grid(3 * DIM / 64, M / 64);  // (12, 128)
    gemm_nt<<<grid, 256, 0, stream>>>(x, Wqkv, nullptr, qkv, M, 3 * DIM, DIM);
  }
  // 2) local attention -> attn [M, 256]
  {
    local_attn<<<BATCH * NHEAD * GRD, 64, 0, stream>>>(qkv, temp, attn);
  }
  // 3) out = attn @ Wproj^T + bproj
  {
    dim3 grid(DIM / 64, M / 64);      // (4, 128)
    gemm_nt<<<grid, 256, 0, stream>>>(attn, Wproj, bproj, out, M, DIM, DIM);
  }
}

// Round 2
// 121.195 us; speedup vs baseline: 1.6724x; 1.6724x over previous
//
#include <hip/hip_runtime.h>
#include <hip/hip_bf16.h>
#include <math.h>

#define DIM   256
#define NHEAD 8
#define HD    32
#define NTOK  4096
#define GRD   64
#define BATCH 2
#define MTOT  (BATCH * NTOK)   // 8192

typedef __attribute__((ext_vector_type(8))) short bf16x8;
typedef __attribute__((ext_vector_type(4))) float f32x4;

static __device__ __forceinline__ unsigned short f2b(float f) {
  __hip_bfloat16 h = __float2bfloat16(f);
  union { __hip_bfloat16 h; unsigned short u; } cv;
  cv.h = h;
  return cv.u;
}

// ---------------- cast fp32 -> bf16 for x, W_qkv, W_proj (one launch) -------
__global__ __launch_bounds__(256) void cast3(const float* __restrict__ x,
                                             const float* __restrict__ wq,
                                             const float* __restrict__ wp,
                                             __hip_bfloat16* __restrict__ xb,
                                             __hip_bfloat16* __restrict__ wqb,
                                             __hip_bfloat16* __restrict__ wpb) {
  const int NX = (MTOT * DIM) / 4;        // 524288 float4s
  const int NQ = (3 * DIM * DIM) / 4;     // 49152
  const int NP = (DIM * DIM) / 4;         // 16384
  int idx = blockIdx.x * 256 + threadIdx.x;
  if (idx >= NX + NQ + NP) return;
  const float* src;
  __hip_bfloat16* dst;
  int off;
  if (idx < NX)            { src = x;  dst = xb;  off = idx; }
  else if (idx < NX + NQ)  { src = wq; dst = wqb; off = idx - NX; }
  else                     { src = wp; dst = wpb; off = idx - NX - NQ; }
  float4 v = *(const float4*)&src[(size_t)off * 4];
  ushort4 o;
  o.x = f2b(v.x); o.y = f2b(v.y); o.z = f2b(v.z); o.w = f2b(v.w);
  *(ushort4*)&dst[(size_t)off * 4] = o;
}

// ---------------- bf16 MFMA GEMM: C = A[M,K] @ Bw[N,K]^T  -------------------
// 128x128 tile, 4 waves (2x2 of 64x64), BK=32, global_load_lds width 16.
// MODE 0: Cout[m*N+n] = acc + bias[n]      (fp32 out)
// MODE 1: scatter into planar qkv fp32: plane = (n>>8)*16 + (m>>12)*8 + ((n&255)>>5),
//         Cout[plane*NTOK*HD + (m&4095)*HD + (n&31)] = acc
template <int MODE>
__global__ __launch_bounds__(256) void gemm_bt(const __hip_bfloat16* __restrict__ A,
                                               const __hip_bfloat16* __restrict__ Bw,
                                               const float* __restrict__ bias,
                                               float* __restrict__ Cout,
                                               int M, int N, int K) {
  __shared__ __hip_bfloat16 As[128 * 32];
  __shared__ __hip_bfloat16 Bs[128 * 32];
  const int tid = threadIdx.x;
  const int l = tid & 63, w = tid >> 6;
  const int bm = blockIdx.y * 128, bn = blockIdx.x * 128;
  const int wr = w >> 1, wc = w & 1;
  const int lr = l & 15, kh = l >> 4;

  f32x4 acc[4][4];
  #pragma unroll
  for (int i = 0; i < 4; ++i)
    #pragma unroll
    for (int j = 0; j < 4; ++j)
      acc[i][j] = (f32x4){0.f, 0.f, 0.f, 0.f};

  const int lrow = l >> 2;          // 0..15: row within 16-row chunk
  const int lcol = (l & 3) * 8;     // 0,8,16,24: k-elems within row

  for (int k0 = 0; k0 < K; k0 += 32) {
    #pragma unroll
    for (int i = 0; i < 2; ++i) {
      const int r0 = (w * 2 + i) * 16;
      const __hip_bfloat16* ga = A  + (size_t)(bm + r0 + lrow) * K + k0 + lcol;
      const __hip_bfloat16* gb = Bw + (size_t)(bn + r0 + lrow) * K + k0 + lcol;
      __builtin_amdgcn_global_load_lds(
          (const __attribute__((address_space(1))) void*)ga,
          (__attribute__((address_space(3))) void*)&As[r0 * 32], 16, 0, 0);
      __builtin_amdgcn_global_load_lds(
          (const __attribute__((address_space(1))) void*)gb,
          (__attribute__((address_space(3))) void*)&Bs[r0 * 32], 16, 0, 0);
    }
    __syncthreads();

    bf16x8 af[4], bfr[4];
    #pragma unroll
    for (int f = 0; f < 4; ++f) {
      af[f]  = *(const bf16x8*)&As[(wr * 64 + f * 16 + lr) * 32 + kh * 8];
      bfr[f] = *(const bf16x8*)&Bs[(wc * 64 + f * 16 + lr) * 32 + kh * 8];
    }
    #pragma unroll
    for (int fi = 0; fi < 4; ++fi)
      #pragma unroll
      for (int fj = 0; fj < 4; ++fj)
        acc[fi][fj] = __builtin_amdgcn_mfma_f32_16x16x32_bf16(af[fi], bfr[fj], acc[fi][fj], 0, 0, 0);
    __syncthreads();
  }

  #pragma unroll
  for (int fi = 0; fi < 4; ++fi) {
    #pragma unroll
    for (int fj = 0; fj < 4; ++fj) {
      #pragma unroll
      for (int rr = 0; rr < 4; ++rr) {
        const int m = bm + wr * 64 + fi * 16 + kh * 4 + rr;
        const int n = bn + wc * 64 + fj * 16 + lr;
        const float v = acc[fi][fj][rr];
        if (MODE == 0) {
          Cout[(size_t)m * N + n] = v + bias[n];
        } else {
          const int sel = n >> 8, rem = n & 255;
          const int hh = rem >> 5, d = rem & 31;
          const int bb = m >> 12, tok = m & 4095;
          Cout[((size_t)(sel * 16 + bb * 8 + hh) * NTOK + tok) * HD + d] = v;
        }
      }
    }
  }
}

// ---------------- Local attention (4 lanes per query) -----------------------
// Planar qkv fp32: plane p = sel*16 + b*8 + h, each [4096][32].
// Block = 256 threads = one (b,h,grid_row r). thread t: query c = t>>2,
// slice s = t&3 over dr: s0:{-3,-2} s1:{-1,0} s2:{1,2} s3:{3}.
// Combine max/sum/PV across the 4 slice-lanes with __shfl_xor(1/2).
__global__ __launch_bounds__(256) void local_attn(const float* __restrict__ qkv,
                                                  const float* __restrict__ temp,
                                                  __hip_bfloat16* __restrict__ attn_out) {
  const int P = blockIdx.x;
  const int L = (P & 7) * 128 + (P >> 3);   // XCD-chunked remap (1024 = 8*128)
  const int b = L >> 9, h = (L >> 6) & 7, r = L & 63;
  const int t = threadIdx.x;
  const int c = t >> 2, s = t & 3;
  const int n = r * GRD + c;

  const float scale = 0.17677669529663687f * temp[0];

  const float* qplane = qkv + (size_t)(b * 8 + h) * (NTOK * HD);
  const float* kplane = qkv + (size_t)(16 + b * 8 + h) * (NTOK * HD);
  const float* vplane = qkv + (size_t)(32 + b * 8 + h) * (NTOK * HD);

  float q[HD];
  {
    const float* qr = qplane + (size_t)n * HD;
    #pragma unroll
    for (int i = 0; i < HD / 4; ++i) {
      float4 v = *(const float4*)&qr[i * 4];
      q[4*i+0] = v.x; q[4*i+1] = v.y; q[4*i+2] = v.z; q[4*i+3] = v.w;
    }
  }

  float sc[14];
  float mx = -INFINITY;
  const int ndr = (s < 3) ? 2 : 1;
  #pragma unroll
  for (int i = 0; i < 2; ++i) {
    const int dr = s * 2 - 3 + i;
    const int rr = r + dr;
    const bool rowok = (i < ndr) && (rr >= 0) && (rr < GRD);
    #pragma unroll
    for (int dc = -3; dc <= 3; ++dc) {
      const int cc = c + dc;
      const bool ok = rowok && (cc >= 0) && (cc < GRD);
      float dot = -INFINITY;
      if (ok) {
        const float* kr = kplane + (size_t)(rr * GRD + cc) * HD;
        dot = 0.f;
        #pragma unroll
        for (int j = 0; j < HD / 4; ++j) {
          float4 kv = *(const float4*)&kr[j * 4];
          dot = fmaf(kv.x, q[4*j+0], dot);
          dot = fmaf(kv.y, q[4*j+1], dot);
          dot = fmaf(kv.z, q[4*j+2], dot);
          dot = fmaf(kv.w, q[4*j+3], dot);
        }
        dot *= scale;
      }
      sc[i * 7 + dc + 3] = dot;
      mx = fmaxf(mx, dot);
    }
  }

  // group (4-lane) max — center key (dr=0,dc=0, slice 1) is always valid,
  // so the combined max is finite.
  mx = fmaxf(mx, __shfl_xor(mx, 1));
  mx = fmaxf(mx, __shfl_xor(mx, 2));

  float psum = 0.f;
  #pragma unroll
  for (int i = 0; i < 14; ++i) {
    float e = __expf(sc[i] - mx);   // exp(-inf - finite) = 0 for masked
    sc[i] = e;
    psum += e;
  }
  psum += __shfl_xor(psum, 1);
  psum += __shfl_xor(psum, 2);
  const float inv = 1.0f / psum;

  float o[HD];
  #pragma unroll
  for (int i = 0; i < HD; ++i) o[i] = 0.f;

  #pragma unroll
  for (int i = 0; i < 2; ++i) {
    const int dr = s * 2 - 3 + i;
    const int rr = r + dr;
    const bool rowok = (i < ndr) && (rr >= 0) && (rr < GRD);
    if (!rowok) continue;
    #pragma unroll
    for (int dc = -3; dc <= 3; ++dc) {
      const int cc = c + dc;
      if (cc < 0 || cc >= GRD) continue;
      const float p = sc[i * 7 + dc + 3];
      const float* vr = vplane + (size_t)(rr * GRD + cc) * HD;
      #pragma unroll
      for (int j = 0; j < HD / 4; ++j) {
        float4 vv = *(const float4*)&vr[j * 4];
        o[4*j+0] = fmaf(p, vv.x, o[4*j+0]);
        o[4*j+1] = fmaf(p, vv.y, o[4*j+1]);
        o[4*j+2] = fmaf(p, vv.z, o[4*j+2]);
        o[4*j+3] = fmaf(p, vv.w, o[4*j+3]);
      }
    }
  }

  // butterfly-combine partial O across the 4 slice-lanes
  #pragma unroll
  for (int d = 0; d < HD; ++d) {
    o[d] += __shfl_xor(o[d], 1);
    o[d] += __shfl_xor(o[d], 2);
  }

  // lane s writes dims [s*8, s*8+8) as bf16 (one 16 B store)
  union { uint4 u; unsigned short sh[8]; } pk;
  #pragma unroll
  for (int j = 0; j < 8; ++j) pk.sh[j] = f2b(o[s * 8 + j] * inv);
  __hip_bfloat16* dst = attn_out + ((size_t)(b * NTOK + n)) * DIM + h * HD + s * 8;
  *(uint4*)dst = pk.u;
}

extern "C" void kernel_launch(void* const* d_in, const int* in_sizes, int n_in,
                              void* d_out, int out_size, void* d_ws, size_t ws_size,
                              hipStream_t stream) {
  const float* x     = (const float*)d_in[0];  // [2,4096,256]
  const float* Wqkv  = (const float*)d_in[1];  // [768,256]
  const float* Wproj = (const float*)d_in[2];  // [256,256]
  const float* bproj = (const float*)d_in[3];  // [256]
  const float* temp  = (const float*)d_in[4];  // [1]
  float* out = (float*)d_out;                  // [2,4096,256] fp32

  // workspace layout (bytes):
  //   [0, 25165824)            qkv planar fp32: 48 planes of [4096][32]
  //   [25165824, 29360128)     x_bf16  (later aliased by attn_bf16 — disjoint lifetimes)
  //   [29360128, 29753344)     Wqkv bf16
  //   [29753344, 29884416)     Wproj bf16
  char* ws = (char*)d_ws;
  float* qkv_planar       = (float*)ws;
  __hip_bfloat16* x_bf    = (__hip_bfloat16*)(ws + 25165824);
  __hip_bfloat16* attn_bf = (__hip_bfloat16*)(ws + 25165824);  // alias, after x_bf dead
  __hip_bfloat16* wq_bf   = (__hip_bfloat16*)(ws + 29360128);
  __hip_bfloat16* wp_bf   = (__hip_bfloat16*)(ws + 29753344);

  // 1) cast inputs to bf16
  cast3<<<2304, 256, 0, stream>>>(x, Wqkv, Wproj, x_bf, wq_bf, wp_bf);

  // 2) qkv = x @ Wqkv^T, scattered into planar fp32 layout
  {
    dim3 grid(3 * DIM / 128, MTOT / 128);  // (6, 64)
    gemm_bt<1><<<grid, 256, 0, stream>>>(x_bf, wq_bf, nullptr, qkv_planar,
                                         MTOT, 3 * DIM, DIM);
  }
  // 3) local attention -> attn_bf [8192][256] bf16 (overwrites x_bf region)
  local_attn<<<BATCH * NHEAD * GRD, 256, 0, stream>>>(qkv_planar, temp, attn_bf);

  // 4) out = attn @ Wproj^T + bias (fp32 out)
  {
    dim3 grid(DIM / 128, MTOT / 128);      // (2, 64)
    gemm_bt<0><<<grid, 256, 0, stream>>>(attn_bf, wp_bf, bproj, out,
                                         MTOT, DIM, DIM);
  }
}

// Round 3
// 56.819 us; speedup vs baseline: 3.5672x; 2.1330x over previous
//
#include <hip/hip_runtime.h>
#include <hip/hip_bf16.h>
#include <hip/hip_fp16.h>
#include <math.h>

#define DIM   256
#define NHEAD 8
#define HD    32
#define NTOK  4096
#define GRD   64
#define BATCH 2
#define MTOT  (BATCH * NTOK)   // 8192

typedef __attribute__((ext_vector_type(8))) short bf16x8;
typedef __attribute__((ext_vector_type(4))) float f32x4;
typedef _Float16 h8 __attribute__((ext_vector_type(8)));
typedef _Float16 h2v __attribute__((ext_vector_type(2)));

#if defined(__has_builtin)
#if __has_builtin(__builtin_amdgcn_fdot2)
#define HAVE_DOT2 1
#endif
#endif
#ifndef HAVE_DOT2
#define HAVE_DOT2 0
#endif

static __device__ __forceinline__ unsigned short f2b(float f) {
  __hip_bfloat16 h = __float2bfloat16(f);
  union { __hip_bfloat16 h; unsigned short u; } cv;
  cv.h = h;
  return cv.u;
}

// ---------------- cast fp32 -> bf16 for x, W_qkv, W_proj (one launch) -------
__global__ __launch_bounds__(256) void cast3(const float* __restrict__ x,
                                             const float* __restrict__ wq,
                                             const float* __restrict__ wp,
                                             __hip_bfloat16* __restrict__ xb,
                                             __hip_bfloat16* __restrict__ wqb,
                                             __hip_bfloat16* __restrict__ wpb) {
  const int NX = (MTOT * DIM) / 4;
  const int NQ = (3 * DIM * DIM) / 4;
  const int NP = (DIM * DIM) / 4;
  int idx = blockIdx.x * 256 + threadIdx.x;
  if (idx >= NX + NQ + NP) return;
  const float* src;
  __hip_bfloat16* dst;
  int off;
  if (idx < NX)            { src = x;  dst = xb;  off = idx; }
  else if (idx < NX + NQ)  { src = wq; dst = wqb; off = idx - NX; }
  else                     { src = wp; dst = wpb; off = idx - NX - NQ; }
  float4 v = *(const float4*)&src[(size_t)off * 4];
  ushort4 o;
  o.x = f2b(v.x); o.y = f2b(v.y); o.z = f2b(v.z); o.w = f2b(v.w);
  *(ushort4*)&dst[(size_t)off * 4] = o;
}

// ---------------- bf16 MFMA GEMM: C = A[M,K] @ Bw[N,K]^T  -------------------
template <int MODE>
__global__ __launch_bounds__(256) void gemm_bt(const __hip_bfloat16* __restrict__ A,
                                               const __hip_bfloat16* __restrict__ Bw,
                                               const float* __restrict__ bias,
                                               float* __restrict__ Cout,
                                               int M, int N, int K) {
  __shared__ __hip_bfloat16 As[128 * 32];
  __shared__ __hip_bfloat16 Bs[128 * 32];
  const int tid = threadIdx.x;
  const int l = tid & 63, w = tid >> 6;
  const int bm = blockIdx.y * 128, bn = blockIdx.x * 128;
  const int wr = w >> 1, wc = w & 1;
  const int lr = l & 15, kh = l >> 4;

  f32x4 acc[4][4];
  #pragma unroll
  for (int i = 0; i < 4; ++i)
    #pragma unroll
    for (int j = 0; j < 4; ++j)
      acc[i][j] = (f32x4){0.f, 0.f, 0.f, 0.f};

  const int lrow = l >> 2;
  const int lcol = (l & 3) * 8;

  for (int k0 = 0; k0 < K; k0 += 32) {
    #pragma unroll
    for (int i = 0; i < 2; ++i) {
      const int r0 = (w * 2 + i) * 16;
      const __hip_bfloat16* ga = A  + (size_t)(bm + r0 + lrow) * K + k0 + lcol;
      const __hip_bfloat16* gb = Bw + (size_t)(bn + r0 + lrow) * K + k0 + lcol;
      __builtin_amdgcn_global_load_lds(
          (const __attribute__((address_space(1))) void*)ga,
          (__attribute__((address_space(3))) void*)&As[r0 * 32], 16, 0, 0);
      __builtin_amdgcn_global_load_lds(
          (const __attribute__((address_space(1))) void*)gb,
          (__attribute__((address_space(3))) void*)&Bs[r0 * 32], 16, 0, 0);
    }
    __syncthreads();

    bf16x8 af[4], bfr[4];
    #pragma unroll
    for (int f = 0; f < 4; ++f) {
      af[f]  = *(const bf16x8*)&As[(wr * 64 + f * 16 + lr) * 32 + kh * 8];
      bfr[f] = *(const bf16x8*)&Bs[(wc * 64 + f * 16 + lr) * 32 + kh * 8];
    }
    #pragma unroll
    for (int fi = 0; fi < 4; ++fi)
      #pragma unroll
      for (int fj = 0; fj < 4; ++fj)
        acc[fi][fj] = __builtin_amdgcn_mfma_f32_16x16x32_bf16(af[fi], bfr[fj], acc[fi][fj], 0, 0, 0);
    __syncthreads();
  }

  #pragma unroll
  for (int fi = 0; fi < 4; ++fi) {
    #pragma unroll
    for (int fj = 0; fj < 4; ++fj) {
      #pragma unroll
      for (int rr = 0; rr < 4; ++rr) {
        const int m = bm + wr * 64 + fi * 16 + kh * 4 + rr;
        const int n = bn + wc * 64 + fj * 16 + lr;
        const float v = acc[fi][fj][rr];
        if (MODE == 0) {
          Cout[(size_t)m * N + n] = v + bias[n];
        } else {
          const int sel = n >> 8, rem = n & 255;
          const int hh = rem >> 5, d = rem & 31;
          const int bb = m >> 12, tok = m & 4095;
          Cout[((size_t)(sel * 16 + bb * 8 + hh) * NTOK + tok) * HD + d] = v;
        }
      }
    }
  }
}

// ---------------- Local attention, LDS-staged K/V (fp16) --------------------
// Block = 256 threads = one (b,h,grid_row r). Stage K/V grid rows r-3..r+3
// (448 tokens x 32 dims) as fp16 in LDS. Row stride 40 halfs (80 B) breaks the
// stride-64B 8-way bank alias; per-dr skew of 8 halfs (16 B) breaks the
// 4-slice-lane same-bank alias. Thread t: query c = t>>2, slice s = t&3 over
// dr {s*2-3, s*2-2} (slice 3: only +3). Combine via __shfl_xor(1/2).
#define LROW 40
#define LSZ  (448 * LROW + 56)

__global__ __launch_bounds__(256) void local_attn(const float* __restrict__ qkv,
                                                  const float* __restrict__ temp,
                                                  __hip_bfloat16* __restrict__ attn_out) {
  __shared__ _Float16 Ks[LSZ];
  __shared__ _Float16 Vs[LSZ];

  const int P = blockIdx.x;
  const int L = (P & 7) * 128 + (P >> 3);   // XCD-chunked remap
  const int b = L >> 9, h = (L >> 6) & 7, r = L & 63;
  const int t = threadIdx.x;
  const int c = t >> 2, s = t & 3;

  const float scale = 0.17677669529663687f * temp[0];

  const float* qplane = qkv + (size_t)(b * 8 + h) * (NTOK * HD);
  const float* kplane = qkv + (size_t)(16 + b * 8 + h) * (NTOK * HD);
  const float* vplane = qkv + (size_t)(32 + b * 8 + h) * (NTOK * HD);

  // ---- stage K/V: 7 chunks of 64 tokens x 32 fp32 (contiguous per chunk) ---
  const int tokloc = t >> 2;
  const int dof = (t & 3) * 8;
  #pragma unroll
  for (int drp = 0; drp < 7; ++drp) {
    const int rr = r - 3 + drp;
    const int widx = (drp * 64 + tokloc) * LROW + drp * 8 + dof;
    h8 hk = 0, hv = 0;
    if (rr >= 0 && rr < GRD) {
      const float* ksrc = kplane + (size_t)rr * (GRD * HD) + t * 8;
      const float* vsrc = vplane + (size_t)rr * (GRD * HD) + t * 8;
      float4 a0 = *(const float4*)ksrc;
      float4 a1 = *(const float4*)(ksrc + 4);
      float4 b0 = *(const float4*)vsrc;
      float4 b1 = *(const float4*)(vsrc + 4);
      hk = (h8){(_Float16)a0.x, (_Float16)a0.y, (_Float16)a0.z, (_Float16)a0.w,
                (_Float16)a1.x, (_Float16)a1.y, (_Float16)a1.z, (_Float16)a1.w};
      hv = (h8){(_Float16)b0.x, (_Float16)b0.y, (_Float16)b0.z, (_Float16)b0.w,
                (_Float16)b1.x, (_Float16)b1.y, (_Float16)b1.z, (_Float16)b1.w};
    }
    *(h8*)&Ks[widx] = hk;
    *(h8*)&Vs[widx] = hv;
  }

  // ---- Q in fp16 pairs -----------------------------------------------------
  h2v q2[16];
  {
    const float* qr = qplane + (size_t)(r * GRD + c) * HD;
    #pragma unroll
    for (int j = 0; j < 8; ++j) {
      float4 v = *(const float4*)&qr[j * 4];
      q2[j * 2 + 0] = (h2v){(_Float16)v.x, (_Float16)v.y};
      q2[j * 2 + 1] = (h2v){(_Float16)v.z, (_Float16)v.w};
    }
  }
  __syncthreads();

  // ---- QK scores -----------------------------------------------------------
  float sc[14];
  int bs[14];
  float mx = -INFINITY;
  const int ndr = (s < 3) ? 2 : 1;
  #pragma unroll
  for (int i = 0; i < 2; ++i) {
    const int dr = s * 2 - 3 + i;
    const int drp = dr + 3;
    const int rr = r + dr;
    const bool rowok = (i < ndr) && (rr >= 0) && (rr < GRD);
    #pragma unroll
    for (int dc = -3; dc <= 3; ++dc) {
      const int cc = c + dc;
      const bool ok = rowok && (cc >= 0) && (cc < GRD);
      int tk = drp * 64 + cc;
      tk = tk < 0 ? 0 : (tk > 447 ? 447 : tk);
      const int base = tk * LROW + drp * 8;
      bs[i * 7 + dc + 3] = base;
      float dot = 0.f;
      #pragma unroll
      for (int jj = 0; jj < 4; ++jj) {
        union { h8 v; h2v p[4]; } kk;
        kk.v = *(const h8*)&Ks[base + jj * 8];
        #pragma unroll
        for (int kx = 0; kx < 4; ++kx) {
#if HAVE_DOT2
          dot = __builtin_amdgcn_fdot2(kk.p[kx], q2[jj * 4 + kx], dot, false);
#else
          dot = fmaf((float)kk.p[kx][0], (float)q2[jj * 4 + kx][0], dot);
          dot = fmaf((float)kk.p[kx][1], (float)q2[jj * 4 + kx][1], dot);
#endif
        }
      }
      const float v = ok ? dot * scale : -INFINITY;
      sc[i * 7 + dc + 3] = v;
      mx = fmaxf(mx, v);
    }
  }

  // group max over the 4 slice-lanes (center key always valid -> finite)
  mx = fmaxf(mx, __shfl_xor(mx, 1));
  mx = fmaxf(mx, __shfl_xor(mx, 2));

  float psum = 0.f;
  #pragma unroll
  for (int i = 0; i < 14; ++i) {
    float e = __expf(sc[i] - mx);   // exp(-inf - finite) = 0 for masked
    sc[i] = e;
    psum += e;
  }
  psum += __shfl_xor(psum, 1);
  psum += __shfl_xor(psum, 2);
  const float inv = 1.0f / psum;

  // ---- PV (branchless; masked p == 0, LDS is NaN-free) ---------------------
  float o[HD];
  #pragma unroll
  for (int i = 0; i < HD; ++i) o[i] = 0.f;

  #pragma unroll
  for (int e = 0; e < 14; ++e) {
    const float p = sc[e];
    const int base = bs[e];
    #pragma unroll
    for (int jj = 0; jj < 4; ++jj) {
      union { h8 v; h2v p2[4]; } vv;
      vv.v = *(const h8*)&Vs[base + jj * 8];
      #pragma unroll
      for (int kx = 0; kx < 4; ++kx) {
        o[jj * 8 + kx * 2 + 0] = fmaf(p, (float)vv.p2[kx][0], o[jj * 8 + kx * 2 + 0]);
        o[jj * 8 + kx * 2 + 1] = fmaf(p, (float)vv.p2[kx][1], o[jj * 8 + kx * 2 + 1]);
      }
    }
  }

  // butterfly-combine partial O across the 4 slice-lanes
  #pragma unroll
  for (int d = 0; d < HD; ++d) {
    o[d] += __shfl_xor(o[d], 1);
    o[d] += __shfl_xor(o[d], 2);
  }

  // lane s writes dims [s*8, s*8+8) as bf16 (one 16 B store)
  union { uint4 u; unsigned short sh[8]; } pk;
  #pragma unroll
  for (int j = 0; j < 8; ++j) pk.sh[j] = f2b(o[s * 8 + j] * inv);
  __hip_bfloat16* dst = attn_out + ((size_t)(b * NTOK + r * GRD + c)) * DIM + h * HD + s * 8;
  *(uint4*)dst = pk.u;
}

extern "C" void kernel_launch(void* const* d_in, const int* in_sizes, int n_in,
                              void* d_out, int out_size, void* d_ws, size_t ws_size,
                              hipStream_t stream) {
  const float* x     = (const float*)d_in[0];
  const float* Wqkv  = (const float*)d_in[1];
  const float* Wproj = (const float*)d_in[2];
  const float* bproj = (const float*)d_in[3];
  const float* temp  = (const float*)d_in[4];
  float* out = (float*)d_out;

  char* ws = (char*)d_ws;
  float* qkv_planar       = (float*)ws;
  __hip_bfloat16* x_bf    = (__hip_bfloat16*)(ws + 25165824);
  __hip_bfloat16* attn_bf = (__hip_bfloat16*)(ws + 25165824);  // alias, after x_bf dead
  __hip_bfloat16* wq_bf   = (__hip_bfloat16*)(ws + 29360128);
  __hip_bfloat16* wp_bf   = (__hip_bfloat16*)(ws + 29753344);

  // 1) cast inputs to bf16
  cast3<<<2304, 256, 0, stream>>>(x, Wqkv, Wproj, x_bf, wq_bf, wp_bf);

  // 2) qkv = x @ Wqkv^T, scattered into planar fp32 layout
  {
    dim3 grid(3 * DIM / 128, MTOT / 128);
    gemm_bt<1><<<grid, 256, 0, stream>>>(x_bf, wq_bf, nullptr, qkv_planar,
                                         MTOT, 3 * DIM, DIM);
  }
  // 3) local attention -> attn_bf [8192][256] bf16
  local_attn<<<BATCH * NHEAD * GRD, 256, 0, stream>>>(qkv_planar, temp, attn_bf);

  // 4) out = attn @ Wproj^T + bias (fp32 out)
  {
    dim3 grid(DIM / 128, MTOT / 128);
    gemm_bt<0><<<grid, 256, 0, stream>>>(attn_bf, wp_bf, bproj, out,
                                         MTOT, DIM, DIM);
  }
}

// Round 6
// 54.574 us; speedup vs baseline: 3.7140x; 1.0411x over previous
//
#include <hip/hip_runtime.h>
#include <hip/hip_bf16.h>
#include <hip/hip_fp16.h>
#include <math.h>

#define DIM   256
#define NHEAD 8
#define HD    32
#define NTOK  4096
#define GRD   64
#define BATCH 2
#define MTOT  (BATCH * NTOK)   // 8192

typedef __attribute__((ext_vector_type(8))) short bf16x8;
typedef __attribute__((ext_vector_type(4))) float f32x4;
typedef _Float16 h8 __attribute__((ext_vector_type(8)));
typedef _Float16 h2v __attribute__((ext_vector_type(2)));

#if defined(__has_builtin)
#if __has_builtin(__builtin_amdgcn_fdot2)
#define HAVE_DOT2 1
#endif
#endif
#ifndef HAVE_DOT2
#define HAVE_DOT2 0
#endif

static __device__ __forceinline__ unsigned short f2b(float f) {
  __hip_bfloat16 h = __float2bfloat16(f);
  union { __hip_bfloat16 h; unsigned short u; } cv;
  cv.h = h;
  return cv.u;
}

// ---------------- cast fp32 -> bf16 for x, W_qkv, W_proj (one launch) -------
__global__ __launch_bounds__(256) void cast3(const float* __restrict__ x,
                                             const float* __restrict__ wq,
                                             const float* __restrict__ wp,
                                             __hip_bfloat16* __restrict__ xb,
                                             __hip_bfloat16* __restrict__ wqb,
                                             __hip_bfloat16* __restrict__ wpb) {
  const int NX = (MTOT * DIM) / 4;
  const int NQ = (3 * DIM * DIM) / 4;
  const int NP = (DIM * DIM) / 4;
  int idx = blockIdx.x * 256 + threadIdx.x;
  if (idx >= NX + NQ + NP) return;
  const float* src;
  __hip_bfloat16* dst;
  int off;
  if (idx < NX)            { src = x;  dst = xb;  off = idx; }
  else if (idx < NX + NQ)  { src = wq; dst = wqb; off = idx - NX; }
  else                     { src = wp; dst = wpb; off = idx - NX - NQ; }
  float4 v = *(const float4*)&src[(size_t)off * 4];
  ushort4 o;
  o.x = f2b(v.x); o.y = f2b(v.y); o.z = f2b(v.z); o.w = f2b(v.w);
  *(ushort4*)&dst[(size_t)off * 4] = o;
}

// ---------------- bf16 MFMA GEMM: C = A[M,K] @ Bw[N,K]^T  -------------------
// MODE 0: fp32 out, +bias.  MODE 1: fp16 planar qkv scatter.
template <int MODE>
__global__ __launch_bounds__(256) void gemm_bt(const __hip_bfloat16* __restrict__ A,
                                               const __hip_bfloat16* __restrict__ Bw,
                                               const float* __restrict__ bias,
                                               void* __restrict__ CoutV,
                                               int M, int N, int K) {
  __shared__ __hip_bfloat16 As[128 * 32];
  __shared__ __hip_bfloat16 Bs[128 * 32];
  const int tid = threadIdx.x;
  const int l = tid & 63, w = tid >> 6;
  const int bm = blockIdx.y * 128, bn = blockIdx.x * 128;
  const int wr = w >> 1, wc = w & 1;
  const int lr = l & 15, kh = l >> 4;

  f32x4 acc[4][4];
  #pragma unroll
  for (int i = 0; i < 4; ++i)
    #pragma unroll
    for (int j = 0; j < 4; ++j)
      acc[i][j] = (f32x4){0.f, 0.f, 0.f, 0.f};

  const int lrow = l >> 2;
  const int lcol = (l & 3) * 8;

  for (int k0 = 0; k0 < K; k0 += 32) {
    #pragma unroll
    for (int i = 0; i < 2; ++i) {
      const int r0 = (w * 2 + i) * 16;
      const __hip_bfloat16* ga = A  + (size_t)(bm + r0 + lrow) * K + k0 + lcol;
      const __hip_bfloat16* gb = Bw + (size_t)(bn + r0 + lrow) * K + k0 + lcol;
      __builtin_amdgcn_global_load_lds(
          (const __attribute__((address_space(1))) void*)ga,
          (__attribute__((address_space(3))) void*)&As[r0 * 32], 16, 0, 0);
      __builtin_amdgcn_global_load_lds(
          (const __attribute__((address_space(1))) void*)gb,
          (__attribute__((address_space(3))) void*)&Bs[r0 * 32], 16, 0, 0);
    }
    __syncthreads();

    bf16x8 af[4], bfr[4];
    #pragma unroll
    for (int f = 0; f < 4; ++f) {
      af[f]  = *(const bf16x8*)&As[(wr * 64 + f * 16 + lr) * 32 + kh * 8];
      bfr[f] = *(const bf16x8*)&Bs[(wc * 64 + f * 16 + lr) * 32 + kh * 8];
    }
    #pragma unroll
    for (int fi = 0; fi < 4; ++fi)
      #pragma unroll
      for (int fj = 0; fj < 4; ++fj)
        acc[fi][fj] = __builtin_amdgcn_mfma_f32_16x16x32_bf16(af[fi], bfr[fj], acc[fi][fj], 0, 0, 0);
    __syncthreads();
  }

  #pragma unroll
  for (int fi = 0; fi < 4; ++fi) {
    #pragma unroll
    for (int fj = 0; fj < 4; ++fj) {
      #pragma unroll
      for (int rr = 0; rr < 4; ++rr) {
        const int m = bm + wr * 64 + fi * 16 + kh * 4 + rr;
        const int n = bn + wc * 64 + fj * 16 + lr;
        const float v = acc[fi][fj][rr];
        if (MODE == 0) {
          ((float*)CoutV)[(size_t)m * N + n] = v + bias[n];
        } else {
          const int sel = n >> 8, rem = n & 255;
          const int hh = rem >> 5, d = rem & 31;
          const int bb = m >> 12, tok = m & 4095;
          ((_Float16*)CoutV)[((size_t)(sel * 16 + bb * 8 + hh) * NTOK + tok) * HD + d] =
              (_Float16)v;
        }
      }
    }
  }
}

// ---------------- Local attention, fp16 K/V via global_load_lds -------------
// Block = 256 threads = one (b,h,grid_row r). K/V rows r-3..r+3 (448 toks x
// 32 halfs = 28 KB each) staged linearly by global_load_lds with XOR-swizzle
// pre-applied to the GLOBAL source (m173 pattern). Physical 16B chunk of
// (tok, jj) is jj ^ x(tok), x = ((tok>>1) ^ (tok>>6)) & 3. Slice s owns dr
// rows {s-3, s+1} (drp = s, s+4) so tok bits 6.. identify the slice.
__global__ __launch_bounds__(256) void local_attn(const _Float16* __restrict__ qkv,
                                                  const float* __restrict__ temp,
                                                  __hip_bfloat16* __restrict__ attn_out) {
  __shared__ _Float16 Ks[448 * 32];
  __shared__ _Float16 Vs[448 * 32];

  const int P = blockIdx.x;
  const int L = (P & 7) * 128 + (P >> 3);   // XCD-chunked remap
  const int b = L >> 9, h = (L >> 6) & 7, r = L & 63;
  const int t = threadIdx.x;
  const int c = t >> 2, s = t & 3;

  const float scale = 0.17677669529663687f * temp[0];

  const _Float16* qplane = qkv + (size_t)(b * 8 + h) * (NTOK * HD);
  const _Float16* kplane = qkv + (size_t)(16 + b * 8 + h) * (NTOK * HD);
  const _Float16* vplane = qkv + (size_t)(32 + b * 8 + h) * (NTOK * HD);

  // ---- stage: thread t = 16B chunk t of dr-row drp. Source pre-swizzled. ---
  {
    const int jjl = (t & 3) ^ ((t >> 3) & 3);   // ^ (drp&3) added per drp
    #pragma unroll
    for (int drp = 0; drp < 7; ++drp) {
      int rr = r - 3 + drp;
      rr = rr < 0 ? 0 : (rr > 63 ? 63 : rr);    // clamp: real finite data
      const int jj = jjl ^ (drp & 3);
      const _Float16* src = kplane + (size_t)rr * 2048 + (t >> 2) * 32 + jj * 8;
      const _Float16* srv = vplane + (size_t)rr * 2048 + (t >> 2) * 32 + jj * 8;
      const int w = t >> 6;
      __builtin_amdgcn_global_load_lds(
          (const __attribute__((address_space(1))) void*)src,
          (__attribute__((address_space(3))) void*)&Ks[(drp * 256 + w * 64) * 8], 16, 0, 0);
      __builtin_amdgcn_global_load_lds(
          (const __attribute__((address_space(1))) void*)srv,
          (__attribute__((address_space(3))) void*)&Vs[(drp * 256 + w * 64) * 8], 16, 0, 0);
    }
  }

  // ---- Q (own query) as fp16 pairs ----------------------------------------
  union { h8 v; h2v p[4]; } qu[4];
  {
    const _Float16* qr = qplane + (size_t)(r * GRD + c) * HD;
    #pragma unroll
    for (int jj = 0; jj < 4; ++jj) qu[jj].v = *(const h8*)&qr[jj * 8];
  }
  __syncthreads();

  // ---- QK scores (slice s: dr = s-3 (i=0), s+1 (i=1, s<3 only)) -----------
  const char* KB = (const char*)Ks;
  const char* VB = (const char*)Vs;
  float sc[14];
  int bs[14];
  float mx = -INFINITY;
  const int ndr = (s < 3) ? 2 : 1;
  #pragma unroll
  for (int i = 0; i < 2; ++i) {
    const int drp = s + i * 4;
    const int rr = r + drp - 3;
    const bool rowok = (i < ndr) && (rr >= 0) && (rr < GRD);
    #pragma unroll
    for (int dc = -3; dc <= 3; ++dc) {
      const int cc = c + dc;
      const bool ok = rowok && (cc >= 0) && (cc < GRD);
      int tk = drp * 64 + cc;
      tk = tk < 0 ? 0 : (tk > 447 ? 447 : tk);
      const int x = ((tk >> 1) ^ (tk >> 6)) & 3;
      const int sb = (tk << 6) ^ (x << 4);      // byte base, bits 4-5 = x
      bs[i * 7 + dc + 3] = sb;
      float dot = 0.f;
      #pragma unroll
      for (int jj = 0; jj < 4; ++jj) {
        union { h8 v; h2v p[4]; } kk;
        kk.v = *(const h8*)(KB + (sb ^ (jj << 4)));
        #pragma unroll
        for (int kx = 0; kx < 4; ++kx) {
#if HAVE_DOT2
          dot = __builtin_amdgcn_fdot2(kk.p[kx], qu[jj].p[kx], dot, false);
#else
          dot = fmaf((float)kk.p[kx][0], (float)qu[jj].p[kx][0], dot);
          dot = fmaf((float)kk.p[kx][1], (float)qu[jj].p[kx][1], dot);
#endif
        }
      }
      const float v = ok ? dot * scale : -INFINITY;
      sc[i * 7 + dc + 3] = v;
      mx = fmaxf(mx, v);
    }
  }

  // group max over the 4 slice-lanes (center key in slice 3 always valid)
  mx = fmaxf(mx, __shfl_xor(mx, 1));
  mx = fmaxf(mx, __shfl_xor(mx, 2));

  float psum = 0.f;
  #pragma unroll
  for (int i = 0; i < 14; ++i) {
    float e = __expf(sc[i] - mx);   // exp(-inf - finite) = 0 for masked
    sc[i] = e;
    psum += e;
  }
  psum += __shfl_xor(psum, 1);
  psum += __shfl_xor(psum, 2);
  const float inv = 1.0f / psum;

  // ---- PV (branchless; masked p == 0, staged data finite) -----------------
  float o[HD];
  #pragma unroll
  for (int i = 0; i < HD; ++i) o[i] = 0.f;

  #pragma unroll
  for (int e = 0; e < 14; ++e) {
    const float p = sc[e];
    const int sb = bs[e];
    #pragma unroll
    for (int jj = 0; jj < 4; ++jj) {
      union { h8 v; h2v p2[4]; } vv;
      vv.v = *(const h8*)(VB + (sb ^ (jj << 4)));
      #pragma unroll
      for (int kx = 0; kx < 4; ++kx) {
        o[jj * 8 + kx * 2 + 0] = fmaf(p, (float)vv.p2[kx][0], o[jj * 8 + kx * 2 + 0]);
        o[jj * 8 + kx * 2 + 1] = fmaf(p, (float)vv.p2[kx][1], o[jj * 8 + kx * 2 + 1]);
      }
    }
  }

  // butterfly-combine partial O across the 4 slice-lanes
  #pragma unroll
  for (int d = 0; d < HD; ++d) {
    o[d] += __shfl_xor(o[d], 1);
    o[d] += __shfl_xor(o[d], 2);
  }

  // lane s writes dims [s*8, s*8+8) as bf16 (one 16 B store)
  union { uint4 u; unsigned short sh[8]; } pk;
  #pragma unroll
  for (int j = 0; j < 8; ++j) pk.sh[j] = f2b(o[s * 8 + j] * inv);
  __hip_bfloat16* dst = attn_out + ((size_t)(b * NTOK + r * GRD + c)) * DIM + h * HD + s * 8;
  *(uint4*)dst = pk.u;
}

extern "C" void kernel_launch(void* const* d_in, const int* in_sizes, int n_in,
                              void* d_out, int out_size, void* d_ws, size_t ws_size,
                              hipStream_t stream) {
  const float* x     = (const float*)d_in[0];
  const float* Wqkv  = (const float*)d_in[1];
  const float* Wproj = (const float*)d_in[2];
  const float* bproj = (const float*)d_in[3];
  const float* temp  = (const float*)d_in[4];
  float* out = (float*)d_out;

  // workspace layout (bytes):
  //   [0, 12582912)            qkv planar fp16: 48 planes of [4096][32]
  //   [25165824, 29360128)     x_bf16 (aliased by attn_bf16 after GEMM1)
  //   [29360128, 29753344)     Wqkv bf16
  //   [29753344, 29884416)     Wproj bf16
  char* ws = (char*)d_ws;
  _Float16* qkv_f16       = (_Float16*)ws;
  __hip_bfloat16* x_bf    = (__hip_bfloat16*)(ws + 25165824);
  __hip_bfloat16* attn_bf = (__hip_bfloat16*)(ws + 25165824);  // alias, x_bf dead
  __hip_bfloat16* wq_bf   = (__hip_bfloat16*)(ws + 29360128);
  __hip_bfloat16* wp_bf   = (__hip_bfloat16*)(ws + 29753344);

  // 1) cast inputs to bf16
  cast3<<<2304, 256, 0, stream>>>(x, Wqkv, Wproj, x_bf, wq_bf, wp_bf);

  // 2) qkv = x @ Wqkv^T -> planar fp16
  {
    dim3 grid(3 * DIM / 128, MTOT / 128);
    gemm_bt<1><<<grid, 256, 0, stream>>>(x_bf, wq_bf, nullptr, qkv_f16,
                                         MTOT, 3 * DIM, DIM);
  }
  // 3) local attention -> attn_bf [8192][256] bf16
  local_attn<<<BATCH * NHEAD * GRD, 256, 0, stream>>>(qkv_f16, temp, attn_bf);

  // 4) out = attn @ Wproj^T + bias (fp32 out)
  {
    dim3 grid(DIM / 128, MTOT / 128);
    gemm_bt<0><<<grid, 256, 0, stream>>>(attn_bf, wp_bf, bproj, out,
                                         MTOT, DIM, DIM);
  }
}

// Round 7
// 49.787 us; speedup vs baseline: 4.0711x; 1.0962x over previous
//
#include <hip/hip_runtime.h>
#include <hip/hip_bf16.h>
#include <hip/hip_fp16.h>
#include <math.h>

#define DIM   256
#define NHEAD 8
#define HD    32
#define NTOK  4096
#define GRD   64
#define BATCH 2
#define MTOT  (BATCH * NTOK)   // 8192

typedef __attribute__((ext_vector_type(8))) short bf16x8;
typedef __attribute__((ext_vector_type(4))) float f32x4;
typedef _Float16 h8 __attribute__((ext_vector_type(8)));
typedef _Float16 h2v __attribute__((ext_vector_type(2)));

#if defined(__has_builtin)
#if __has_builtin(__builtin_amdgcn_fdot2)
#define HAVE_DOT2 1
#endif
#endif
#ifndef HAVE_DOT2
#define HAVE_DOT2 0
#endif

static __device__ __forceinline__ unsigned short f2b(float f) {
  __hip_bfloat16 h = __float2bfloat16(f);
  union { __hip_bfloat16 h; unsigned short u; } cv;
  cv.h = h;
  return cv.u;
}

static __device__ __forceinline__ bf16x8 pack8(float4 a0, float4 a1) {
  union { bf16x8 v; unsigned short u[8]; } o;
  o.u[0] = f2b(a0.x); o.u[1] = f2b(a0.y); o.u[2] = f2b(a0.z); o.u[3] = f2b(a0.w);
  o.u[4] = f2b(a1.x); o.u[5] = f2b(a1.y); o.u[6] = f2b(a1.z); o.u[7] = f2b(a1.w);
  return o.v;
}

// ---------------- GEMM1: qkv = x(fp32) @ Wqkv(fp32)^T -> planar fp16 --------
// 128x128 tile, BK=32, 4 waves. Both operands cast fp32->bf16 during
// reg-staging (LDS pitch 40 halfs = 80 B: bank = row*20 mod 32, full spread).
__global__ __launch_bounds__(256) void gemm_qkv(const float* __restrict__ A,
                                                const float* __restrict__ Bw,
                                                _Float16* __restrict__ Cout) {
  const int K = 256, N = 768;
  __shared__ __hip_bfloat16 As[128 * 40];
  __shared__ __hip_bfloat16 Bs[128 * 40];
  const int tid = threadIdx.x;
  const int l = tid & 63, w = tid >> 6;
  const int bm = blockIdx.y * 128, bn = blockIdx.x * 128;
  const int wr = w >> 1, wc = w & 1;
  const int lr = l & 15, kh = l >> 4;
  const int lrow = l >> 2, lcol = (l & 3) * 8;

  f32x4 acc[4][4];
  #pragma unroll
  for (int i = 0; i < 4; ++i)
    #pragma unroll
    for (int j = 0; j < 4; ++j)
      acc[i][j] = (f32x4){0.f, 0.f, 0.f, 0.f};

  for (int k0 = 0; k0 < K; k0 += 32) {
    #pragma unroll
    for (int i = 0; i < 2; ++i) {
      const int r0 = (w * 2 + i) * 16;
      const float* ga = A  + (size_t)(bm + r0 + lrow) * K + k0 + lcol;
      const float* gb = Bw + (size_t)(bn + r0 + lrow) * K + k0 + lcol;
      float4 a0 = *(const float4*)ga, a1 = *(const float4*)(ga + 4);
      float4 b0 = *(const float4*)gb, b1 = *(const float4*)(gb + 4);
      *(bf16x8*)&As[(r0 + lrow) * 40 + lcol] = pack8(a0, a1);
      *(bf16x8*)&Bs[(r0 + lrow) * 40 + lcol] = pack8(b0, b1);
    }
    __syncthreads();

    bf16x8 af[4], bfr[4];
    #pragma unroll
    for (int f = 0; f < 4; ++f) {
      af[f]  = *(const bf16x8*)&As[(wr * 64 + f * 16 + lr) * 40 + kh * 8];
      bfr[f] = *(const bf16x8*)&Bs[(wc * 64 + f * 16 + lr) * 40 + kh * 8];
    }
    #pragma unroll
    for (int fi = 0; fi < 4; ++fi)
      #pragma unroll
      for (int fj = 0; fj < 4; ++fj)
        acc[fi][fj] = __builtin_amdgcn_mfma_f32_16x16x32_bf16(af[fi], bfr[fj], acc[fi][fj], 0, 0, 0);
    __syncthreads();
  }

  #pragma unroll
  for (int fi = 0; fi < 4; ++fi)
    #pragma unroll
    for (int fj = 0; fj < 4; ++fj)
      #pragma unroll
      for (int rr = 0; rr < 4; ++rr) {
        const int m = bm + wr * 64 + fi * 16 + kh * 4 + rr;
        const int n = bn + wc * 64 + fj * 16 + lr;
        const int sel = n >> 8, rem = n & 255;
        const int hh = rem >> 5, d = rem & 31;
        const int bb = m >> 12, tok = m & 4095;
        Cout[((size_t)(sel * 16 + bb * 8 + hh) * NTOK + tok) * HD + d] =
            (_Float16)acc[fi][fj][rr];
      }
}

// ---------------- GEMM2: out = attn(bf16) @ Wproj(fp32)^T + bias (fp32) -----
__global__ __launch_bounds__(256) void gemm_proj(const __hip_bfloat16* __restrict__ A,
                                                 const float* __restrict__ Bw,
                                                 const float* __restrict__ bias,
                                                 float* __restrict__ Cout) {
  const int K = 256, N = 256;
  __shared__ __hip_bfloat16 As[128 * 32];   // linear: global_load_lds dest
  __shared__ __hip_bfloat16 Bs[128 * 40];   // padded: reg-staged
  const int tid = threadIdx.x;
  const int l = tid & 63, w = tid >> 6;
  const int bm = blockIdx.y * 128, bn = blockIdx.x * 128;
  const int wr = w >> 1, wc = w & 1;
  const int lr = l & 15, kh = l >> 4;
  const int lrow = l >> 2, lcol = (l & 3) * 8;

  f32x4 acc[4][4];
  #pragma unroll
  for (int i = 0; i < 4; ++i)
    #pragma unroll
    for (int j = 0; j < 4; ++j)
      acc[i][j] = (f32x4){0.f, 0.f, 0.f, 0.f};

  for (int k0 = 0; k0 < K; k0 += 32) {
    #pragma unroll
    for (int i = 0; i < 2; ++i) {
      const int r0 = (w * 2 + i) * 16;
      const __hip_bfloat16* ga = A + (size_t)(bm + r0 + lrow) * K + k0 + lcol;
      __builtin_amdgcn_global_load_lds(
          (const __attribute__((address_space(1))) void*)ga,
          (__attribute__((address_space(3))) void*)&As[r0 * 32], 16, 0, 0);
      const float* gb = Bw + (size_t)(bn + r0 + lrow) * K + k0 + lcol;
      float4 b0 = *(const float4*)gb, b1 = *(const float4*)(gb + 4);
      *(bf16x8*)&Bs[(r0 + lrow) * 40 + lcol] = pack8(b0, b1);
    }
    __syncthreads();

    bf16x8 af[4], bfr[4];
    #pragma unroll
    for (int f = 0; f < 4; ++f) {
      af[f]  = *(const bf16x8*)&As[(wr * 64 + f * 16 + lr) * 32 + kh * 8];
      bfr[f] = *(const bf16x8*)&Bs[(wc * 64 + f * 16 + lr) * 40 + kh * 8];
    }
    #pragma unroll
    for (int fi = 0; fi < 4; ++fi)
      #pragma unroll
      for (int fj = 0; fj < 4; ++fj)
        acc[fi][fj] = __builtin_amdgcn_mfma_f32_16x16x32_bf16(af[fi], bfr[fj], acc[fi][fj], 0, 0, 0);
    __syncthreads();
  }

  #pragma unroll
  for (int fi = 0; fi < 4; ++fi)
    #pragma unroll
    for (int fj = 0; fj < 4; ++fj)
      #pragma unroll
      for (int rr = 0; rr < 4; ++rr) {
        const int m = bm + wr * 64 + fi * 16 + kh * 4 + rr;
        const int n = bn + wc * 64 + fj * 16 + lr;
        Cout[(size_t)m * N + n] = acc[fi][fj][rr] + bias[n];
      }
}

// ---------------- Local attention: 2 query-rows per block -------------------
// Block = 512 threads = one (b,h,row-pair rp) -> query rows 2rp, 2rp+1.
// Stage K/V rows 2rp-3..2rp+4 (512 toks x 32 halfs = 32 KB each) via
// global_load_lds, XOR swizzle x = ((tk>>1)^(tk>>6))&3 pre-applied to the
// global source and re-applied on read. Thread t: qr=t>>8, c=(t>>2)&63,
// slice s=t&3 over dr {s-3, s+1}; combine via __shfl_xor(1/2).
__global__ __launch_bounds__(512) void local_attn(const _Float16* __restrict__ qkv,
                                                  const float* __restrict__ temp,
                                                  __hip_bfloat16* __restrict__ attn_out) {
  __shared__ _Float16 Ks[512 * 32];
  __shared__ _Float16 Vs[512 * 32];

  const int P = blockIdx.x;
  const int L = (P & 7) * 64 + (P >> 3);    // XCD-chunked remap (512 = 8*64)
  const int plane = L >> 5, rp = L & 31;
  const int b = plane >> 3, h = plane & 7;
  const int t = threadIdx.x;
  const int qr = t >> 8, c = (t >> 2) & 63, s = t & 3;
  const int r = rp * 2 + qr;

  const float scale = 0.17677669529663687f * temp[0];

  const _Float16* qplane = qkv + (size_t)(b * 8 + h) * (NTOK * HD);
  const _Float16* kplane = qkv + (size_t)(16 + b * 8 + h) * (NTOK * HD);
  const _Float16* vplane = qkv + (size_t)(32 + b * 8 + h) * (NTOK * HD);

  // ---- stage 8 grid rows of K/V (clamped), source pre-swizzled -------------
  {
    const int rbase = rp * 2 - 3;
    const int wbase = t & ~63;              // wave-uniform
    #pragma unroll
    for (int i = 0; i < 4; ++i) {
      const int id = i * 512 + t;
      const int drp = id >> 8;              // 0..7 (wave-uniform)
      const int tokloc = (id >> 2) & 63;
      const int jjp = id & 3;
      const int x = ((tokloc >> 1) ^ drp) & 3;
      const int jj = jjp ^ x;
      int row = rbase + drp;
      row = row < 0 ? 0 : (row > 63 ? 63 : row);
      const _Float16* src = kplane + (size_t)row * 2048 + tokloc * 32 + jj * 8;
      const _Float16* srv = vplane + (size_t)row * 2048 + tokloc * 32 + jj * 8;
      const int dbase = (i * 512 + wbase) * 8;
      __builtin_amdgcn_global_load_lds(
          (const __attribute__((address_space(1))) void*)src,
          (__attribute__((address_space(3))) void*)&Ks[dbase], 16, 0, 0);
      __builtin_amdgcn_global_load_lds(
          (const __attribute__((address_space(1))) void*)srv,
          (__attribute__((address_space(3))) void*)&Vs[dbase], 16, 0, 0);
    }
  }

  // ---- Q (own query) as fp16 pairs ----------------------------------------
  union { h8 v; h2v p[4]; } qu[4];
  {
    const _Float16* qrp_ = qplane + (size_t)(r * GRD + c) * HD;
    #pragma unroll
    for (int jj = 0; jj < 4; ++jj) qu[jj].v = *(const h8*)&qrp_[jj * 8];
  }
  __syncthreads();

  // ---- QK scores (slice s: dr = s-3 (i=0), s+1 (i=1, s<3 only)) -----------
  const char* KB = (const char*)Ks;
  const char* VB = (const char*)Vs;
  float sc[14];
  int bs[14];
  float mx = -INFINITY;
  const int ndr = (s < 3) ? 2 : 1;
  #pragma unroll
  for (int i = 0; i < 2; ++i) {
    const int dr = s - 3 + 4 * i;
    const int drp = dr + 3 + qr;            // staged row index 0..7
    const int rr = r + dr;
    const bool rowok = (i < ndr) && (rr >= 0) && (rr < GRD);
    #pragma unroll
    for (int dc = -3; dc <= 3; ++dc) {
      const int cc = c + dc;
      const bool ok = rowok && (cc >= 0) && (cc < GRD);
      int tk = drp * 64 + cc;
      tk = tk < 0 ? 0 : (tk > 511 ? 511 : tk);
      const int x = ((tk >> 1) ^ (tk >> 6)) & 3;
      const int sb = (tk << 6) ^ (x << 4);  // byte base, bits 4-5 swizzled
      bs[i * 7 + dc + 3] = sb;
      float dot = 0.f;
      #pragma unroll
      for (int jj = 0; jj < 4; ++jj) {
        union { h8 v; h2v p[4]; } kk;
        kk.v = *(const h8*)(KB + (sb ^ (jj << 4)));
        #pragma unroll
        for (int kx = 0; kx < 4; ++kx) {
#if HAVE_DOT2
          dot = __builtin_amdgcn_fdot2(kk.p[kx], qu[jj].p[kx], dot, false);
#else
          dot = fmaf((float)kk.p[kx][0], (float)qu[jj].p[kx][0], dot);
          dot = fmaf((float)kk.p[kx][1], (float)qu[jj].p[kx][1], dot);
#endif
        }
      }
      const float v = ok ? dot * scale : -INFINITY;
      sc[i * 7 + dc + 3] = v;
      mx = fmaxf(mx, v);
    }
  }

  // group max over the 4 slice-lanes (center key, slice 3 i=0, always valid)
  mx = fmaxf(mx, __shfl_xor(mx, 1));
  mx = fmaxf(mx, __shfl_xor(mx, 2));

  float psum = 0.f;
  #pragma unroll
  for (int i = 0; i < 14; ++i) {
    float e = __expf(sc[i] - mx);   // exp(-inf - finite) = 0 for masked
    sc[i] = e;
    psum += e;
  }
  psum += __shfl_xor(psum, 1);
  psum += __shfl_xor(psum, 2);
  const float inv = 1.0f / psum;

  // ---- PV (branchless; masked p == 0, staged data finite) -----------------
  float o[HD];
  #pragma unroll
  for (int i = 0; i < HD; ++i) o[i] = 0.f;

  #pragma unroll
  for (int e = 0; e < 14; ++e) {
    const float p = sc[e];
    const int sb = bs[e];
    #pragma unroll
    for (int jj = 0; jj < 4; ++jj) {
      union { h8 v; h2v p2[4]; } vv;
      vv.v = *(const h8*)(VB + (sb ^ (jj << 4)));
      #pragma unroll
      for (int kx = 0; kx < 4; ++kx) {
        o[jj * 8 + kx * 2 + 0] = fmaf(p, (float)vv.p2[kx][0], o[jj * 8 + kx * 2 + 0]);
        o[jj * 8 + kx * 2 + 1] = fmaf(p, (float)vv.p2[kx][1], o[jj * 8 + kx * 2 + 1]);
      }
    }
  }

  // butterfly-combine partial O across the 4 slice-lanes
  #pragma unroll
  for (int d = 0; d < HD; ++d) {
    o[d] += __shfl_xor(o[d], 1);
    o[d] += __shfl_xor(o[d], 2);
  }

  // lane s writes dims [s*8, s*8+8) as bf16 (one 16 B store)
  union { uint4 u; unsigned short sh[8]; } pk;
  #pragma unroll
  for (int j = 0; j < 8; ++j) pk.sh[j] = f2b(o[s * 8 + j] * inv);
  __hip_bfloat16* dst = attn_out + ((size_t)(b * NTOK + r * GRD + c)) * DIM + h * HD + s * 8;
  *(uint4*)dst = pk.u;
}

extern "C" void kernel_launch(void* const* d_in, const int* in_sizes, int n_in,
                              void* d_out, int out_size, void* d_ws, size_t ws_size,
                              hipStream_t stream) {
  const float* x     = (const float*)d_in[0];
  const float* Wqkv  = (const float*)d_in[1];
  const float* Wproj = (const float*)d_in[2];
  const float* bproj = (const float*)d_in[3];
  const float* temp  = (const float*)d_in[4];
  float* out = (float*)d_out;

  // workspace layout (bytes):
  //   [0, 12582912)            qkv planar fp16: 48 planes of [4096][32]
  //   [25165824, 29360128)     attn_bf16 [8192][256]
  char* ws = (char*)d_ws;
  _Float16* qkv_f16       = (_Float16*)ws;
  __hip_bfloat16* attn_bf = (__hip_bfloat16*)(ws + 25165824);

  // 1) qkv = x @ Wqkv^T (fused fp32->bf16 cast) -> planar fp16
  {
    dim3 grid(3 * DIM / 128, MTOT / 128);   // (6, 64)
    gemm_qkv<<<grid, 256, 0, stream>>>(x, Wqkv, qkv_f16);
  }
  // 2) local attention -> attn_bf [8192][256] bf16
  local_attn<<<BATCH * NHEAD * (GRD / 2), 512, 0, stream>>>(qkv_f16, temp, attn_bf);

  // 3) out = attn @ Wproj^T + bias (fused Wproj cast, fp32 out)
  {
    dim3 grid(DIM / 128, MTOT / 128);       // (2, 64)
    gemm_proj<<<grid, 256, 0, stream>>>(attn_bf, Wproj, bproj, out);
  }
}